// Round 4
// baseline (350.686 us; speedup 1.0000x reference)
//
#include <hip/hip_runtime.h>
#include <math.h>

// TransformLoss on MI355X — round-2 kernel (resubmitted; broker timeouts in r2/r3).
// Math (per row, d1 = init_img - next_img, d2 = init_unclip - pred_unclip):
//   A=sum d1^2, C=sum d2^2, AB=sum d1*d2, S1=sum d1, S2=sum d2
//   cos = clip(AB/(sqrt(A)sqrt(C)),-1,1); sin_a = sqrt(1-cos^2); cm1 = cos-1
//   k = AB/A; W = C - AB*k; rA=1/sqrt(A); rW=1/sqrt(W)
//   s1 = S1*rA; s2 = (S2 - S1*k)*rW
//   p = cm1*s1 - sin_a*s2; q = sin_a*s1 + cm1*s2
//   u[d] = d1[d]*(p*rA - q*k*rW) + d2[d]*(q*rW)
//   loss_u[d] = 0.5 * nan_to_num( sum_rows(mask * u^2) / cnt )
//   mse[d]    = 0.5 * mean_rows( (d1-d2)^2 )
//
// Round-2 changes (latency-bound at 14% HBM, 17.5% occupancy in round 1):
//  - 1024 blocks (4096 waves, 4 rows/wave) for 2-4x more waves/CU
//  - software pipeline: next row's 12 float4 loads issued BEFORE the
//    5-value butterfly, so the shfl chain overlaps in-flight vmem
//  - per-block partial writes (plain stores) + reduce kernel instead of
//    512-way contended global atomics; zero_ws kernel deleted

constexpr int D      = 768;
constexpr int B_ROWS = 16384;
constexpr int BDIM   = 256;             // 4 waves / block
constexpr int NBLK   = 1024;            // 4096 waves
constexpr int WPB    = BDIM / 64;       // waves per block = 4
constexpr int RPW    = B_ROWS / (NBLK * WPB);   // rows per wave = 4

// PARTIALS layout in ws:
//   ws[blk*1536 + 0..767]   = block partial sum of u^2 (masked)
//   ws[blk*1536 + 768..1535]= block partial sum of (d1-d2)^2
//   ws[NBLK*1536 + blk]     = block partial mask count
// Fallback (ATOMIC) layout: ws[0..1535] accumulators, ws[1536] cnt (zeroed first).

__global__ void zero_ws_kernel(float* __restrict__ ws, int n) {
    int i = blockIdx.x * blockDim.x + threadIdx.x;
    if (i < n) ws[i] = 0.0f;
}

template <bool PARTIALS>
__global__ __launch_bounds__(BDIM)
void transform_loss_main(const float* __restrict__ g_init_img,
                         const float* __restrict__ g_next_img,
                         const float* __restrict__ g_init_unclip,
                         const float* __restrict__ g_pred_unclip,
                         float* __restrict__ ws)
{
    const int lane  = threadIdx.x & 63;
    const int wave  = threadIdx.x >> 6;
    const int gwave = blockIdx.x * WPB + wave;
    const int row0  = gwave * RPW;

    float acc_u[12], acc_m[12];
#pragma unroll
    for (int i = 0; i < 12; ++i) { acc_u[i] = 0.f; acc_m[i] = 0.f; }
    float local_cnt = 0.f;

    const size_t base0 = (size_t)row0 * D + (size_t)(lane * 4);

    // prologue: load row0
    float4 va[3], vb[3], vc[3], vd[3];
#pragma unroll
    for (int t = 0; t < 3; ++t) {
        va[t] = *(const float4*)(g_init_img    + base0 + t * 256);
        vb[t] = *(const float4*)(g_next_img    + base0 + t * 256);
        vc[t] = *(const float4*)(g_init_unclip + base0 + t * 256);
        vd[t] = *(const float4*)(g_pred_unclip + base0 + t * 256);
    }

#pragma unroll
    for (int r = 0; r < RPW; ++r) {
        // consume current row's vectors into diffs + 5 partial sums
        float d1[12], d2[12];
        float sA = 0.f, sC = 0.f, sAB = 0.f, sS1 = 0.f, sS2 = 0.f;
#pragma unroll
        for (int t = 0; t < 3; ++t) {
            const float a4[4] = {va[t].x, va[t].y, va[t].z, va[t].w};
            const float b4[4] = {vb[t].x, vb[t].y, vb[t].z, vb[t].w};
            const float c4[4] = {vc[t].x, vc[t].y, vc[t].z, vc[t].w};
            const float e4[4] = {vd[t].x, vd[t].y, vd[t].z, vd[t].w};
#pragma unroll
            for (int j = 0; j < 4; ++j) {
                float x = a4[j] - b4[j];
                float y = c4[j] - e4[j];
                d1[t * 4 + j] = x; d2[t * 4 + j] = y;
                sA  = fmaf(x, x, sA);
                sC  = fmaf(y, y, sC);
                sAB = fmaf(x, y, sAB);
                sS1 += x;
                sS2 += y;
            }
        }
        // issue next row's loads BEFORE the butterfly (overlap shfl chain)
        if (r + 1 < RPW) {
            const size_t bn = base0 + (size_t)(r + 1) * D;
#pragma unroll
            for (int t = 0; t < 3; ++t) {
                va[t] = *(const float4*)(g_init_img    + bn + t * 256);
                vb[t] = *(const float4*)(g_next_img    + bn + t * 256);
                vc[t] = *(const float4*)(g_init_unclip + bn + t * 256);
                vd[t] = *(const float4*)(g_pred_unclip + bn + t * 256);
            }
        }
        // 5-value wave64 butterfly reduction
#pragma unroll
        for (int m = 1; m < 64; m <<= 1) {
            sA  += __shfl_xor(sA,  m);
            sC  += __shfl_xor(sC,  m);
            sAB += __shfl_xor(sAB, m);
            sS1 += __shfl_xor(sS1, m);
            sS2 += __shfl_xor(sS2, m);
        }
        // mse over FULL batch (no mask)
#pragma unroll
        for (int i = 0; i < 12; ++i) {
            float dd = d1[i] - d2[i];
            acc_m[i] = fmaf(dd, dd, acc_m[i]);
        }
        if (sA > 1e-16f) {   // ||d1|| > 1e-8
            local_cnt += 1.f;
            float nA  = sqrtf(sA);
            float rA  = 1.f / nA;
            float nC  = sqrtf(sC);
            float cosang = sAB / (nA * nC);
            cosang = fminf(fmaxf(cosang, -1.f), 1.f);
            float sin_a = sqrtf(fmaxf(1.f - cosang * cosang, 0.f));
            float cm1 = cosang - 1.f;
            float k  = sAB / sA;
            float W  = sC - sAB * k;        // C - AB^2/A
            float rW = 1.f / sqrtf(W);
            float s1 = sS1 * rA;
            float s2 = (sS2 - sS1 * k) * rW;
            float p  = cm1 * s1 - sin_a * s2;
            float q  = sin_a * s1 + cm1 * s2;
            float c1 = p * rA - q * k * rW;
            float c2 = q * rW;
#pragma unroll
            for (int i = 0; i < 12; ++i) {
                float u = fmaf(d1[i], c1, d2[i] * c2);
                acc_u[i] = fmaf(u, u, acc_u[i]);
            }
        }
    }

    // block-level reduction in LDS
    __shared__ float sh[2 * D];
    __shared__ float shcnt;
    if (threadIdx.x == 0) shcnt = 0.f;
    for (int i = threadIdx.x; i < 2 * D; i += BDIM) sh[i] = 0.f;
    __syncthreads();
#pragma unroll
    for (int t = 0; t < 3; ++t)
#pragma unroll
        for (int j = 0; j < 4; ++j) {
            int dIdx = t * 256 + lane * 4 + j;
            atomicAdd(&sh[dIdx],     acc_u[t * 4 + j]);
            atomicAdd(&sh[D + dIdx], acc_m[t * 4 + j]);
        }
    if (lane == 0) atomicAdd(&shcnt, local_cnt);
    __syncthreads();

    if (PARTIALS) {
        float* pb = ws + (size_t)blockIdx.x * (2 * D);
        for (int i = threadIdx.x; i < 2 * D; i += BDIM) pb[i] = sh[i];
        if (threadIdx.x == 0) ws[(size_t)NBLK * 2 * D + blockIdx.x] = shcnt;
    } else {
        for (int i = threadIdx.x; i < 2 * D; i += BDIM) atomicAdd(&ws[i], sh[i]);
        if (threadIdx.x == 0) atomicAdd(&ws[2 * D], shcnt);
    }
}

template <bool PARTIALS>
__global__ __launch_bounds__(BDIM)
void finalize_kernel(const float* __restrict__ ws, float* __restrict__ out)
{
    const int i = blockIdx.x * BDIM + threadIdx.x;   // 0..1535 (grid = 6 blocks)
    float cnt, s;
    if (PARTIALS) {
        // block-redundant reduce of the 1024 per-block counts
        float c = 0.f;
        for (int r = threadIdx.x; r < NBLK; r += BDIM)
            c += ws[(size_t)NBLK * 2 * D + r];
#pragma unroll
        for (int m = 1; m < 64; m <<= 1) c += __shfl_xor(c, m);
        __shared__ float sc[WPB];
        if ((threadIdx.x & 63) == 0) sc[threadIdx.x >> 6] = c;
        __syncthreads();
        c = 0.f;
#pragma unroll
        for (int wv = 0; wv < WPB; ++wv) c += sc[wv];
        cnt = fmaxf(c, 1.f);

        // column-i sum over 1024 block partials (coalesced across threads)
        float s0 = 0.f, s1 = 0.f, s2 = 0.f, s3 = 0.f;
        for (int r = 0; r < NBLK; r += 4) {
            s0 += ws[(size_t)(r + 0) * 2 * D + i];
            s1 += ws[(size_t)(r + 1) * 2 * D + i];
            s2 += ws[(size_t)(r + 2) * 2 * D + i];
            s3 += ws[(size_t)(r + 3) * 2 * D + i];
        }
        s = (s0 + s1) + (s2 + s3);
    } else {
        cnt = fmaxf(ws[2 * D], 1.f);
        s = ws[i];
    }

    if (i < D) {
        float lu = s / cnt;
        // jnp.nan_to_num(nan=0, posinf=0.1, neginf=-0.1)
        if (isnan(lu)) lu = 0.f;
        else if (isinf(lu)) lu = (lu > 0.f) ? 0.1f : -0.1f;
        out[i] = 0.5f * lu;                      // WEIGHT_ROTE * loss_u
    } else {
        out[i] = 0.5f * (s * (1.f / 16384.f));   // WEIGHT_MSE * mse (loss_I == 0)
    }
}

extern "C" void kernel_launch(void* const* d_in, const int* in_sizes, int n_in,
                              void* d_out, int out_size, void* d_ws, size_t ws_size,
                              hipStream_t stream) {
    const float* init_img    = (const float*)d_in[0];
    const float* next_img    = (const float*)d_in[1];
    const float* init_unclip = (const float*)d_in[2];
    const float* pred_unclip = (const float*)d_in[3];
    float* ws  = (float*)d_ws;
    float* out = (float*)d_out;

    const size_t need = ((size_t)NBLK * 2 * D + NBLK) * sizeof(float);
    if (ws_size >= need) {
        transform_loss_main<true><<<NBLK, BDIM, 0, stream>>>(
            init_img, next_img, init_unclip, pred_unclip, ws);
        finalize_kernel<true><<<(2 * D) / BDIM, BDIM, 0, stream>>>(ws, out);
    } else {
        zero_ws_kernel<<<(2 * D + 1 + BDIM - 1) / BDIM, BDIM, 0, stream>>>(ws, 2 * D + 1);
        transform_loss_main<false><<<NBLK, BDIM, 0, stream>>>(
            init_img, next_img, init_unclip, pred_unclip, ws);
        finalize_kernel<false><<<(2 * D) / BDIM, BDIM, 0, stream>>>(ws, out);
    }
}

// Round 5
// 252.531 us; speedup vs baseline: 1.3887x; 1.3887x over previous
//
#include <hip/hip_runtime.h>
#include <math.h>

// TransformLoss on MI355X — round 5.
// Math (per row, d1 = init_img - next_img, d2 = init_unclip - pred_unclip):
//   A=sum d1^2, C=sum d2^2, AB=sum d1*d2, S1=sum d1, S2=sum d2
//   cos = clip(AB/(sqrt(A)sqrt(C)),-1,1); sin_a = sqrt(1-cos^2); cm1 = cos-1
//   k = AB/A; W = C - AB*k; rA=1/sqrt(A); rW=1/sqrt(W)
//   s1 = S1*rA; s2 = (S2 - S1*k)*rW
//   p = cm1*s1 - sin_a*s2; q = sin_a*s1 + cm1*s2
//   u[d] = d1[d]*(p*rA - q*k*rW) + d2[d]*(q*rW)
//   loss_u[d] = 0.5 * nan_to_num( sum_rows(mask * u^2) / cnt )
//   mse[d]    = 0.5 * mean_rows( (d1-d2)^2 )
//
// Round-5 changes:
//  - r4 evidence: finalize_kernel=139us (6 blocks, 1024-deep column sums,
//    0.25% occupancy) and main likely unchanged ~91us at VGPR=52 — the
//    12-load prefetch could never materialize in 52 registers, so loads
//    serialized in 4-load chunks (3 sequential HBM latencies per row).
//  - main: __launch_bounds__(256,4) -> VGPR cap 128, 16 waves/CU (matches
//    4 blocks/CU x 4 waves). Pipeline now fits in registers.
//  - finalize: two-stage tree (96-block row-group reduce, then 6-block
//    final) replacing the single 6-block 1024-deep reduce.

constexpr int D      = 768;
constexpr int B_ROWS = 16384;
constexpr int BDIM   = 256;             // 4 waves / block
constexpr int NBLK   = 1024;            // 4096 waves
constexpr int WPB    = BDIM / 64;       // waves per block = 4
constexpr int RPW    = B_ROWS / (NBLK * WPB);   // rows per wave = 4
constexpr int RG     = 64;              // rows per stage-A group
constexpr int NRG    = NBLK / RG;       // 16 stage-A groups

// ws layout (floats):
//   [0 .. NBLK*1536)                 P1: per-block partials (u^2 | mse)
//   [CNT_OFF .. CNT_OFF+NBLK)        per-block mask counts
//   [P2_OFF .. P2_OFF+NRG*1536)     P2: stage-A row-group partials
constexpr size_t CNT_OFF = (size_t)NBLK * 2 * D;
constexpr size_t P2_OFF  = CNT_OFF + NBLK;

__global__ void zero_ws_kernel(float* __restrict__ ws, int n) {
    int i = blockIdx.x * blockDim.x + threadIdx.x;
    if (i < n) ws[i] = 0.0f;
}

template <bool PARTIALS>
__global__ __launch_bounds__(BDIM, 4)   // 4 waves/EU min -> VGPR cap 128
void transform_loss_main(const float* __restrict__ g_init_img,
                         const float* __restrict__ g_next_img,
                         const float* __restrict__ g_init_unclip,
                         const float* __restrict__ g_pred_unclip,
                         float* __restrict__ ws)
{
    const int lane  = threadIdx.x & 63;
    const int wave  = threadIdx.x >> 6;
    const int gwave = blockIdx.x * WPB + wave;
    const int row0  = gwave * RPW;

    float acc_u[12], acc_m[12];
#pragma unroll
    for (int i = 0; i < 12; ++i) { acc_u[i] = 0.f; acc_m[i] = 0.f; }
    float local_cnt = 0.f;

    const size_t base0 = (size_t)row0 * D + (size_t)(lane * 4);

    // prologue: load row0 (12 float4 = 48 VGPRs in flight)
    float4 va[3], vb[3], vc[3], vd[3];
#pragma unroll
    for (int t = 0; t < 3; ++t) {
        va[t] = *(const float4*)(g_init_img    + base0 + t * 256);
        vb[t] = *(const float4*)(g_next_img    + base0 + t * 256);
        vc[t] = *(const float4*)(g_init_unclip + base0 + t * 256);
        vd[t] = *(const float4*)(g_pred_unclip + base0 + t * 256);
    }

#pragma unroll
    for (int r = 0; r < RPW; ++r) {
        // consume current row's vectors into diffs + 5 partial sums
        float d1[12], d2[12];
        float sA = 0.f, sC = 0.f, sAB = 0.f, sS1 = 0.f, sS2 = 0.f;
#pragma unroll
        for (int t = 0; t < 3; ++t) {
            const float a4[4] = {va[t].x, va[t].y, va[t].z, va[t].w};
            const float b4[4] = {vb[t].x, vb[t].y, vb[t].z, vb[t].w};
            const float c4[4] = {vc[t].x, vc[t].y, vc[t].z, vc[t].w};
            const float e4[4] = {vd[t].x, vd[t].y, vd[t].z, vd[t].w};
#pragma unroll
            for (int j = 0; j < 4; ++j) {
                float x = a4[j] - b4[j];
                float y = c4[j] - e4[j];
                d1[t * 4 + j] = x; d2[t * 4 + j] = y;
                sA  = fmaf(x, x, sA);
                sC  = fmaf(y, y, sC);
                sAB = fmaf(x, y, sAB);
                sS1 += x;
                sS2 += y;
            }
        }
        // issue next row's loads BEFORE the butterfly (overlap shfl chain)
        if (r + 1 < RPW) {
            const size_t bn = base0 + (size_t)(r + 1) * D;
#pragma unroll
            for (int t = 0; t < 3; ++t) {
                va[t] = *(const float4*)(g_init_img    + bn + t * 256);
                vb[t] = *(const float4*)(g_next_img    + bn + t * 256);
                vc[t] = *(const float4*)(g_init_unclip + bn + t * 256);
                vd[t] = *(const float4*)(g_pred_unclip + bn + t * 256);
            }
        }
        // 5-value wave64 butterfly reduction
#pragma unroll
        for (int m = 1; m < 64; m <<= 1) {
            sA  += __shfl_xor(sA,  m);
            sC  += __shfl_xor(sC,  m);
            sAB += __shfl_xor(sAB, m);
            sS1 += __shfl_xor(sS1, m);
            sS2 += __shfl_xor(sS2, m);
        }
        // mse over FULL batch (no mask)
#pragma unroll
        for (int i = 0; i < 12; ++i) {
            float dd = d1[i] - d2[i];
            acc_m[i] = fmaf(dd, dd, acc_m[i]);
        }
        if (sA > 1e-16f) {   // ||d1|| > 1e-8
            local_cnt += 1.f;
            float nA  = sqrtf(sA);
            float rA  = 1.f / nA;
            float nC  = sqrtf(sC);
            float cosang = sAB / (nA * nC);
            cosang = fminf(fmaxf(cosang, -1.f), 1.f);
            float sin_a = sqrtf(fmaxf(1.f - cosang * cosang, 0.f));
            float cm1 = cosang - 1.f;
            float k  = sAB / sA;
            float W  = sC - sAB * k;        // C - AB^2/A
            float rW = 1.f / sqrtf(W);
            float s1 = sS1 * rA;
            float s2 = (sS2 - sS1 * k) * rW;
            float p  = cm1 * s1 - sin_a * s2;
            float q  = sin_a * s1 + cm1 * s2;
            float c1 = p * rA - q * k * rW;
            float c2 = q * rW;
#pragma unroll
            for (int i = 0; i < 12; ++i) {
                float u = fmaf(d1[i], c1, d2[i] * c2);
                acc_u[i] = fmaf(u, u, acc_u[i]);
            }
        }
    }

    // block-level reduction in LDS
    __shared__ float sh[2 * D];
    __shared__ float shcnt;
    if (threadIdx.x == 0) shcnt = 0.f;
    for (int i = threadIdx.x; i < 2 * D; i += BDIM) sh[i] = 0.f;
    __syncthreads();
#pragma unroll
    for (int t = 0; t < 3; ++t)
#pragma unroll
        for (int j = 0; j < 4; ++j) {
            int dIdx = t * 256 + lane * 4 + j;
            atomicAdd(&sh[dIdx],     acc_u[t * 4 + j]);
            atomicAdd(&sh[D + dIdx], acc_m[t * 4 + j]);
        }
    if (lane == 0) atomicAdd(&shcnt, local_cnt);
    __syncthreads();

    if (PARTIALS) {
        float* pb = ws + (size_t)blockIdx.x * (2 * D);
        for (int i = threadIdx.x; i < 2 * D; i += BDIM) pb[i] = sh[i];
        if (threadIdx.x == 0) ws[CNT_OFF + blockIdx.x] = shcnt;
    } else {
        for (int i = threadIdx.x; i < 2 * D; i += BDIM) atomicAdd(&ws[i], sh[i]);
        if (threadIdx.x == 0) atomicAdd(&ws[2 * D], shcnt);
    }
}

// Stage A: 96 blocks (6 col-groups x 16 row-groups); each thread sums RG=64
// rows of one column. Coalesced across threads; 384 waves of parallelism.
__global__ __launch_bounds__(BDIM)
void reduce_partials(const float* __restrict__ ws_in, float* __restrict__ ws_out)
{
    const int c  = blockIdx.x * BDIM + threadIdx.x;   // 0..1535
    const int rg = blockIdx.y;                        // 0..NRG-1
    const float* p = ws_in + (size_t)rg * RG * (2 * D) + c;
    float s0 = 0.f, s1 = 0.f, s2 = 0.f, s3 = 0.f;
#pragma unroll 4
    for (int r = 0; r < RG; r += 4) {
        s0 += p[(size_t)(r + 0) * (2 * D)];
        s1 += p[(size_t)(r + 1) * (2 * D)];
        s2 += p[(size_t)(r + 2) * (2 * D)];
        s3 += p[(size_t)(r + 3) * (2 * D)];
    }
    ws_out[P2_OFF + (size_t)rg * (2 * D) + c] = (s0 + s1) + (s2 + s3);
}

// Stage B: 6 blocks; 16-deep sum over P2 + count reduce + output transform.
__global__ __launch_bounds__(BDIM)
void finalize_tree(const float* __restrict__ ws, float* __restrict__ out)
{
    const int i = blockIdx.x * BDIM + threadIdx.x;    // 0..1535

    // reduce the NBLK per-block mask counts (redundant per block, cheap)
    float c = 0.f;
    for (int r = threadIdx.x; r < NBLK; r += BDIM) c += ws[CNT_OFF + r];
#pragma unroll
    for (int m = 1; m < 64; m <<= 1) c += __shfl_xor(c, m);
    __shared__ float sc[WPB];
    if ((threadIdx.x & 63) == 0) sc[threadIdx.x >> 6] = c;
    __syncthreads();
    float cnt = fmaxf((sc[0] + sc[1]) + (sc[2] + sc[3]), 1.f);

    float s = 0.f;
#pragma unroll
    for (int g = 0; g < NRG; ++g) s += ws[P2_OFF + (size_t)g * (2 * D) + i];

    if (i < D) {
        float lu = s / cnt;
        // jnp.nan_to_num(nan=0, posinf=0.1, neginf=-0.1)
        if (isnan(lu)) lu = 0.f;
        else if (isinf(lu)) lu = (lu > 0.f) ? 0.1f : -0.1f;
        out[i] = 0.5f * lu;                      // WEIGHT_ROTE * loss_u
    } else {
        out[i] = 0.5f * (s * (1.f / 16384.f));   // WEIGHT_MSE * mse (loss_I == 0)
    }
}

// Atomic fallback finalize (tiny ws): ws[0..1535] sums, ws[1536] cnt.
__global__ __launch_bounds__(BDIM)
void finalize_atomic(const float* __restrict__ ws, float* __restrict__ out)
{
    const int i = blockIdx.x * BDIM + threadIdx.x;
    float cnt = fmaxf(ws[2 * D], 1.f);
    float s = ws[i];
    if (i < D) {
        float lu = s / cnt;
        if (isnan(lu)) lu = 0.f;
        else if (isinf(lu)) lu = (lu > 0.f) ? 0.1f : -0.1f;
        out[i] = 0.5f * lu;
    } else {
        out[i] = 0.5f * (s * (1.f / 16384.f));
    }
}

extern "C" void kernel_launch(void* const* d_in, const int* in_sizes, int n_in,
                              void* d_out, int out_size, void* d_ws, size_t ws_size,
                              hipStream_t stream) {
    const float* init_img    = (const float*)d_in[0];
    const float* next_img    = (const float*)d_in[1];
    const float* init_unclip = (const float*)d_in[2];
    const float* pred_unclip = (const float*)d_in[3];
    float* ws  = (float*)d_ws;
    float* out = (float*)d_out;

    const size_t need = (P2_OFF + (size_t)NRG * 2 * D) * sizeof(float);
    if (ws_size >= need) {
        transform_loss_main<true><<<NBLK, BDIM, 0, stream>>>(
            init_img, next_img, init_unclip, pred_unclip, ws);
        reduce_partials<<<dim3(2 * D / BDIM, NRG), BDIM, 0, stream>>>(ws, ws);
        finalize_tree<<<2 * D / BDIM, BDIM, 0, stream>>>(ws, out);
    } else {
        zero_ws_kernel<<<(2 * D + 1 + BDIM - 1) / BDIM, BDIM, 0, stream>>>(ws, 2 * D + 1);
        transform_loss_main<false><<<NBLK, BDIM, 0, stream>>>(
            init_img, next_img, init_unclip, pred_unclip, ws);
        finalize_atomic<<<2 * D / BDIM, BDIM, 0, stream>>>(ws, out);
    }
}

// Round 6
// 251.212 us; speedup vs baseline: 1.3960x; 1.0052x over previous
//
#include <hip/hip_runtime.h>
#include <math.h>

// TransformLoss on MI355X — round 6.
// Math (per row, d1 = init_img - next_img, d2 = init_unclip - pred_unclip):
//   A=sum d1^2, C=sum d2^2, AB=sum d1*d2, S1=sum d1, S2=sum d2
//   cos = clip(AB/(sqrt(A)sqrt(C)),-1,1); sin_a = sqrt(1-cos^2); cm1 = cos-1
//   k = AB/A; W = C - AB*k; rA=1/sqrt(A); rW=1/sqrt(W)
//   s1 = S1*rA; s2 = (S2 - S1*k)*rW
//   p = cm1*s1 - sin_a*s2; q = sin_a*s1 + cm1*s2
//   u[d] = d1[d]*(p*rA - q*k*rW) + d2[d]*(q*rW)
//   loss_u[d] = 0.5 * nan_to_num( sum_rows(mask * u^2) / cnt )
//   mse[d]    = 0.5 * mean_rows( (d1-d2)^2 )
//
// Round-6 changes (evidence from r5: VGPR=64 + 82 MB scratch spill traffic —
// the source-level 12-load prefetch spilled; occupancy 35% helped despite it):
//  - REVERT to the round-1 loop body (proven 52 VGPR, zero spills; the 12
//    loads of one row already issue back-to-back before first use).
//  - TLP instead of per-wave MLP: 1024 blocks x 512 threads (8 waves/block,
//    2 rows/wave) -> 4 blocks/CU x 8 waves = 32 waves/CU = 100% occupancy cap
//    (r1 was capped at 25%, r5 at 50%).
//  - keep r5's two-stage reduce tree (finalize cost now negligible).

constexpr int D      = 768;
constexpr int B_ROWS = 16384;
constexpr int BDIM   = 512;             // 8 waves / block
constexpr int NBLK   = 1024;            // 8192 waves total
constexpr int WPB    = BDIM / 64;       // waves per block = 8
constexpr int RPW    = B_ROWS / (NBLK * WPB);   // rows per wave = 2
constexpr int RG     = 64;              // rows per stage-A group
constexpr int NRG    = NBLK / RG;       // 16 stage-A groups

// ws layout (floats):
//   [0 .. NBLK*1536)                 P1: per-block partials (u^2 | mse)
//   [CNT_OFF .. CNT_OFF+NBLK)        per-block mask counts
//   [P2_OFF .. P2_OFF+NRG*1536)     P2: stage-A row-group partials
constexpr size_t CNT_OFF = (size_t)NBLK * 2 * D;
constexpr size_t P2_OFF  = CNT_OFF + NBLK;

__global__ void zero_ws_kernel(float* __restrict__ ws, int n) {
    int i = blockIdx.x * blockDim.x + threadIdx.x;
    if (i < n) ws[i] = 0.0f;
}

template <bool PARTIALS>
__global__ __launch_bounds__(BDIM)
void transform_loss_main(const float* __restrict__ g_init_img,
                         const float* __restrict__ g_next_img,
                         const float* __restrict__ g_init_unclip,
                         const float* __restrict__ g_pred_unclip,
                         float* __restrict__ ws)
{
    const int lane  = threadIdx.x & 63;
    const int wave  = threadIdx.x >> 6;
    const int gwave = blockIdx.x * WPB + wave;

    float acc_u[12], acc_m[12];
#pragma unroll
    for (int i = 0; i < 12; ++i) { acc_u[i] = 0.f; acc_m[i] = 0.f; }
    float local_cnt = 0.f;

#pragma unroll
    for (int r = 0; r < RPW; ++r) {
        const int row = gwave * RPW + r;
        const size_t base = (size_t)row * D + (size_t)(lane * 4);

        // 12 independent float4 loads issue back-to-back (no prefetch
        // across rows — r5 proved that spills; TLP hides the latency).
        float4 va[3], vb[3], vc[3], vd[3];
#pragma unroll
        for (int t = 0; t < 3; ++t) {
            va[t] = *(const float4*)(g_init_img    + base + t * 256);
            vb[t] = *(const float4*)(g_next_img    + base + t * 256);
            vc[t] = *(const float4*)(g_init_unclip + base + t * 256);
            vd[t] = *(const float4*)(g_pred_unclip + base + t * 256);
        }

        float d1[12], d2[12];
        float sA = 0.f, sC = 0.f, sAB = 0.f, sS1 = 0.f, sS2 = 0.f;
#pragma unroll
        for (int t = 0; t < 3; ++t) {
            const float a4[4] = {va[t].x, va[t].y, va[t].z, va[t].w};
            const float b4[4] = {vb[t].x, vb[t].y, vb[t].z, vb[t].w};
            const float c4[4] = {vc[t].x, vc[t].y, vc[t].z, vc[t].w};
            const float e4[4] = {vd[t].x, vd[t].y, vd[t].z, vd[t].w};
#pragma unroll
            for (int j = 0; j < 4; ++j) {
                float x = a4[j] - b4[j];
                float y = c4[j] - e4[j];
                d1[t * 4 + j] = x; d2[t * 4 + j] = y;
                sA  = fmaf(x, x, sA);
                sC  = fmaf(y, y, sC);
                sAB = fmaf(x, y, sAB);
                sS1 += x;
                sS2 += y;
            }
        }
        // 5-value wave64 butterfly reduction
#pragma unroll
        for (int m = 1; m < 64; m <<= 1) {
            sA  += __shfl_xor(sA,  m);
            sC  += __shfl_xor(sC,  m);
            sAB += __shfl_xor(sAB, m);
            sS1 += __shfl_xor(sS1, m);
            sS2 += __shfl_xor(sS2, m);
        }
        // mse over FULL batch (no mask)
#pragma unroll
        for (int i = 0; i < 12; ++i) {
            float dd = d1[i] - d2[i];
            acc_m[i] = fmaf(dd, dd, acc_m[i]);
        }
        if (sA > 1e-16f) {   // ||d1|| > 1e-8
            local_cnt += 1.f;
            float nA  = sqrtf(sA);
            float rA  = 1.f / nA;
            float nC  = sqrtf(sC);
            float cosang = sAB / (nA * nC);
            cosang = fminf(fmaxf(cosang, -1.f), 1.f);
            float sin_a = sqrtf(fmaxf(1.f - cosang * cosang, 0.f));
            float cm1 = cosang - 1.f;
            float k  = sAB / sA;
            float W  = sC - sAB * k;        // C - AB^2/A
            float rW = 1.f / sqrtf(W);
            float s1 = sS1 * rA;
            float s2 = (sS2 - sS1 * k) * rW;
            float p  = cm1 * s1 - sin_a * s2;
            float q  = sin_a * s1 + cm1 * s2;
            float c1 = p * rA - q * k * rW;
            float c2 = q * rW;
#pragma unroll
            for (int i = 0; i < 12; ++i) {
                float u = fmaf(d1[i], c1, d2[i] * c2);
                acc_u[i] = fmaf(u, u, acc_u[i]);
            }
        }
    }

    // block-level reduction in LDS (8 waves share each address; 1536 addrs)
    __shared__ float sh[2 * D];
    __shared__ float shcnt;
    if (threadIdx.x == 0) shcnt = 0.f;
    for (int i = threadIdx.x; i < 2 * D; i += BDIM) sh[i] = 0.f;
    __syncthreads();
#pragma unroll
    for (int t = 0; t < 3; ++t)
#pragma unroll
        for (int j = 0; j < 4; ++j) {
            int dIdx = t * 256 + lane * 4 + j;
            atomicAdd(&sh[dIdx],     acc_u[t * 4 + j]);
            atomicAdd(&sh[D + dIdx], acc_m[t * 4 + j]);
        }
    if (lane == 0) atomicAdd(&shcnt, local_cnt);
    __syncthreads();

    if (PARTIALS) {
        float* pb = ws + (size_t)blockIdx.x * (2 * D);
        for (int i = threadIdx.x; i < 2 * D; i += BDIM) pb[i] = sh[i];
        if (threadIdx.x == 0) ws[CNT_OFF + blockIdx.x] = shcnt;
    } else {
        for (int i = threadIdx.x; i < 2 * D; i += BDIM) atomicAdd(&ws[i], sh[i]);
        if (threadIdx.x == 0) atomicAdd(&ws[2 * D], shcnt);
    }
}

// Stage A: grid (3, NRG); each thread sums RG=64 rows of one column.
__global__ __launch_bounds__(BDIM)
void reduce_partials(const float* __restrict__ ws_in, float* __restrict__ ws_out)
{
    const int c  = blockIdx.x * BDIM + threadIdx.x;   // 0..1535
    const int rg = blockIdx.y;                        // 0..NRG-1
    if (c >= 2 * D) return;
    const float* p = ws_in + (size_t)rg * RG * (2 * D) + c;
    float s0 = 0.f, s1 = 0.f, s2 = 0.f, s3 = 0.f;
#pragma unroll 4
    for (int r = 0; r < RG; r += 4) {
        s0 += p[(size_t)(r + 0) * (2 * D)];
        s1 += p[(size_t)(r + 1) * (2 * D)];
        s2 += p[(size_t)(r + 2) * (2 * D)];
        s3 += p[(size_t)(r + 3) * (2 * D)];
    }
    ws_out[P2_OFF + (size_t)rg * (2 * D) + c] = (s0 + s1) + (s2 + s3);
}

// Stage B: NRG-deep sum over P2 + count reduce + output transform.
__global__ __launch_bounds__(BDIM)
void finalize_tree(const float* __restrict__ ws, float* __restrict__ out)
{
    const int i = blockIdx.x * BDIM + threadIdx.x;    // 0..1535
    // reduce the NBLK per-block mask counts (redundant per block, cheap)
    float c = 0.f;
    for (int r = threadIdx.x; r < NBLK; r += BDIM) c += ws[CNT_OFF + r];
#pragma unroll
    for (int m = 1; m < 64; m <<= 1) c += __shfl_xor(c, m);
    __shared__ float sc[WPB];
    if ((threadIdx.x & 63) == 0) sc[threadIdx.x >> 6] = c;
    __syncthreads();
    float csum = 0.f;
#pragma unroll
    for (int wv = 0; wv < WPB; ++wv) csum += sc[wv];
    float cnt = fmaxf(csum, 1.f);

    if (i >= 2 * D) return;
    float s = 0.f;
#pragma unroll
    for (int g = 0; g < NRG; ++g) s += ws[P2_OFF + (size_t)g * (2 * D) + i];

    if (i < D) {
        float lu = s / cnt;
        // jnp.nan_to_num(nan=0, posinf=0.1, neginf=-0.1)
        if (isnan(lu)) lu = 0.f;
        else if (isinf(lu)) lu = (lu > 0.f) ? 0.1f : -0.1f;
        out[i] = 0.5f * lu;                      // WEIGHT_ROTE * loss_u
    } else {
        out[i] = 0.5f * (s * (1.f / 16384.f));   // WEIGHT_MSE * mse (loss_I == 0)
    }
}

// Atomic fallback finalize (tiny ws): ws[0..1535] sums, ws[1536] cnt.
__global__ __launch_bounds__(BDIM)
void finalize_atomic(const float* __restrict__ ws, float* __restrict__ out)
{
    const int i = blockIdx.x * BDIM + threadIdx.x;
    if (i >= 2 * D) return;
    float cnt = fmaxf(ws[2 * D], 1.f);
    float s = ws[i];
    if (i < D) {
        float lu = s / cnt;
        if (isnan(lu)) lu = 0.f;
        else if (isinf(lu)) lu = (lu > 0.f) ? 0.1f : -0.1f;
        out[i] = 0.5f * lu;
    } else {
        out[i] = 0.5f * (s * (1.f / 16384.f));
    }
}

extern "C" void kernel_launch(void* const* d_in, const int* in_sizes, int n_in,
                              void* d_out, int out_size, void* d_ws, size_t ws_size,
                              hipStream_t stream) {
    const float* init_img    = (const float*)d_in[0];
    const float* next_img    = (const float*)d_in[1];
    const float* init_unclip = (const float*)d_in[2];
    const float* pred_unclip = (const float*)d_in[3];
    float* ws  = (float*)d_ws;
    float* out = (float*)d_out;

    const size_t need = (P2_OFF + (size_t)NRG * 2 * D) * sizeof(float);
    if (ws_size >= need) {
        transform_loss_main<true><<<NBLK, BDIM, 0, stream>>>(
            init_img, next_img, init_unclip, pred_unclip, ws);
        reduce_partials<<<dim3((2 * D + BDIM - 1) / BDIM, NRG), BDIM, 0, stream>>>(ws, ws);
        finalize_tree<<<(2 * D + BDIM - 1) / BDIM, BDIM, 0, stream>>>(ws, out);
    } else {
        zero_ws_kernel<<<(2 * D + 1 + BDIM - 1) / BDIM, BDIM, 0, stream>>>(ws, 2 * D + 1);
        transform_loss_main<false><<<NBLK, BDIM, 0, stream>>>(
            init_img, next_img, init_unclip, pred_unclip, ws);
        finalize_atomic<<<(2 * D + BDIM - 1) / BDIM, BDIM, 0, stream>>>(ws, out);
    }
}

// Round 12
// 219.159 us; speedup vs baseline: 1.6001x; 1.1463x over previous
//
#include <hip/hip_runtime.h>
#include <math.h>

// TransformLoss on MI355X — round 7 kernel (5th resubmit; broker/container
// failures in r7-r11 — kernel still unmeasured).
// Math (per row, d1 = init_img - next_img, d2 = init_unclip - pred_unclip):
//   A=sum d1^2, C=sum d2^2, AB=sum d1*d2, S1=sum d1, S2=sum d2
//   k=AB/A; W=C-AB*k; rA=1/sqrt(A); rW=1/sqrt(W); cos=clip(AB/(sqrt(A)sqrt(C)))
//   sin_a=sqrt(1-cos^2); cm1=cos-1; s1=S1*rA; s2=(S2-S1*k)*rW
//   p=cm1*s1-sin_a*s2; q=sin_a*s1+cm1*s2; c1=p*rA-q*k*rW; c2=q*rW
//   u[d]=c1*d1[d]+c2*d2[d]
//   loss_u[d]=0.5*nan_to_num(sum_masked u^2 / cnt); mse[d]=0.5*mean((d1-d2)^2)
//
// Round-7 redesign (r6 evidence: VGPR=52 with 48 needed for d1/d2/acc =>
// ~1 load in flight per wave; latency-bound at 893 GB/s, VALUBusy 7%):
//  - 2 columns per thread (float2), block=384 threads covers a full row.
//    Base pressure ~45 VGPR -> loads have register headroom.
//  - register-neutral prefetch: diffs consume va..vd, next row's loads
//    overwrite them immediately, butterfly+LDS+accum hides the latency.
//  - 5-scalar row reduction: 6-step wave butterfly + 1 LDS exchange,
//    double-buffered -> exactly 1 barrier per row.
//  - epilogue: thread owns its 2 columns -> plain coalesced float2 partial
//    stores (LDS-atomic epilogue deleted).
//  - NBLK=1024 (partials 6.3 MB, fits ws per r4), 6144 waves = 24/CU.

constexpr int D      = 768;
constexpr int B_ROWS = 16384;
constexpr int BDIM   = 384;             // 6 waves; thread covers 2 columns
constexpr int WPB    = BDIM / 64;       // 6 waves per block
constexpr int NBLK   = 1024;
constexpr int RPB    = B_ROWS / NBLK;   // 16 rows per block
constexpr int BDIM_R = 256;             // reduce kernels
constexpr int RG     = 64;              // rows per stage-A group
constexpr int NRG    = NBLK / RG;       // 16

// ws layout (floats):
//   [0 .. NBLK*1536)              P1: per-block partials (u^2[768] | mse[768])
//   [CNT_OFF .. CNT_OFF+NBLK)     per-block mask counts
//   [P2_OFF .. P2_OFF+NRG*1536)   P2: stage-A row-group partials
constexpr size_t CNT_OFF = (size_t)NBLK * 2 * D;
constexpr size_t P2_OFF  = CNT_OFF + NBLK;

__global__ void zero_ws_kernel(float* __restrict__ ws, int n) {
    int i = blockIdx.x * blockDim.x + threadIdx.x;
    if (i < n) ws[i] = 0.0f;
}

template <bool PARTIALS>
__global__ __launch_bounds__(BDIM)
void transform_loss_main(const float* __restrict__ gA,   // init_img
                         const float* __restrict__ gB,   // next_img
                         const float* __restrict__ gC,   // init_unclip
                         const float* __restrict__ gE,   // pred_unclip
                         float* __restrict__ ws)
{
    const int t    = threadIdx.x;
    const int lane = t & 63;
    const int wave = t >> 6;

    float au0 = 0.f, au1 = 0.f, am0 = 0.f, am1 = 0.f, lcnt = 0.f;

    __shared__ float red[2][WPB][8];   // 5 scalars used, padded to 8 (32B align)

    size_t base = (size_t)blockIdx.x * RPB * D + (size_t)(2 * t);
    float2 va = *(const float2*)(gA + base);
    float2 vb = *(const float2*)(gB + base);
    float2 vc = *(const float2*)(gC + base);
    float2 ve = *(const float2*)(gE + base);

#pragma unroll
    for (int r = 0; r < RPB; ++r) {
        // consume current row's vectors
        const float d1x = va.x - vb.x, d1y = va.y - vb.y;
        const float d2x = vc.x - ve.x, d2y = vc.y - ve.y;
        // register-neutral prefetch of next row (overwrites va..ve)
        if (r + 1 < RPB) {
            base += D;
            va = *(const float2*)(gA + base);
            vb = *(const float2*)(gB + base);
            vc = *(const float2*)(gC + base);
            ve = *(const float2*)(gE + base);
        }
        // 5 per-thread partials over this thread's 2 columns
        float pA  = fmaf(d1x, d1x, d1y * d1y);
        float pC  = fmaf(d2x, d2x, d2y * d2y);
        float pAB = fmaf(d1x, d2x, d1y * d2y);
        float pS1 = d1x + d1y;
        float pS2 = d2x + d2y;
        // wave butterfly
#pragma unroll
        for (int m = 1; m < 64; m <<= 1) {
            pA  += __shfl_xor(pA,  m);
            pC  += __shfl_xor(pC,  m);
            pAB += __shfl_xor(pAB, m);
            pS1 += __shfl_xor(pS1, m);
            pS2 += __shfl_xor(pS2, m);
        }
        // cross-wave combine: leaders write 5 floats, 1 barrier (dbuf slots)
        if (lane == 0) {
            red[r & 1][wave][0] = pA;
            red[r & 1][wave][1] = pC;
            red[r & 1][wave][2] = pAB;
            red[r & 1][wave][3] = pS1;
            red[r & 1][wave][4] = pS2;
        }
        __syncthreads();
        float sA = 0.f, sC = 0.f, sAB = 0.f, sS1 = 0.f, sS2 = 0.f;
#pragma unroll
        for (int w = 0; w < WPB; ++w) {
            const float4 q = *(const float4*)&red[r & 1][w][0];  // 32B-aligned
            sA  += q.x; sC += q.y; sAB += q.z; sS1 += q.w;
            sS2 += red[r & 1][w][4];
        }
        // mse over FULL batch
        const float mdx = d1x - d2x, mdy = d1y - d2y;
        am0 = fmaf(mdx, mdx, am0);
        am1 = fmaf(mdy, mdy, am1);
        // masked rotation-loss accumulate (branch is block-uniform)
        if (sA > 1e-16f) {   // ||d1|| > 1e-8
            lcnt += 1.f;
            const float nA  = sqrtf(sA);
            const float rA  = 1.f / nA;
            const float nC  = sqrtf(sC);
            float cosang = sAB / (nA * nC);
            cosang = fminf(fmaxf(cosang, -1.f), 1.f);
            const float sin_a = sqrtf(fmaxf(1.f - cosang * cosang, 0.f));
            const float cm1 = cosang - 1.f;
            const float k   = sAB / sA;
            const float W   = sC - sAB * k;        // C - AB^2/A
            const float rW  = 1.f / sqrtf(W);
            const float s1  = sS1 * rA;
            const float s2  = (sS2 - sS1 * k) * rW;
            const float p   = cm1 * s1 - sin_a * s2;
            const float q   = sin_a * s1 + cm1 * s2;
            const float c1  = p * rA - q * k * rW;
            const float c2  = q * rW;
            const float ux = fmaf(d1x, c1, d2x * c2);
            const float uy = fmaf(d1y, c1, d2y * c2);
            au0 = fmaf(ux, ux, au0);
            au1 = fmaf(uy, uy, au1);
        }
    }

    // epilogue: thread owns columns 2t,2t+1 -> plain coalesced stores
    if (PARTIALS) {
        float* pb = ws + (size_t)blockIdx.x * (2 * D);
        *(float2*)(pb + 2 * t)     = make_float2(au0, au1);
        *(float2*)(pb + D + 2 * t) = make_float2(am0, am1);
        if (t == 0) ws[CNT_OFF + blockIdx.x] = lcnt;   // block-uniform value
    } else {
        atomicAdd(&ws[2 * t],         au0);
        atomicAdd(&ws[2 * t + 1],     au1);
        atomicAdd(&ws[D + 2 * t],     am0);
        atomicAdd(&ws[D + 2 * t + 1], am1);
        if (t == 0) atomicAdd(&ws[2 * D], lcnt);
    }
}

// Stage A: grid (6, NRG); each thread sums RG=64 rows of one column.
__global__ __launch_bounds__(BDIM_R)
void reduce_partials(const float* __restrict__ ws_in, float* __restrict__ ws_out)
{
    const int c  = blockIdx.x * BDIM_R + threadIdx.x;   // 0..1535
    const int rg = blockIdx.y;                          // 0..NRG-1
    if (c >= 2 * D) return;
    const float* p = ws_in + (size_t)rg * RG * (2 * D) + c;
    float s0 = 0.f, s1 = 0.f, s2 = 0.f, s3 = 0.f;
#pragma unroll 4
    for (int r = 0; r < RG; r += 4) {
        s0 += p[(size_t)(r + 0) * (2 * D)];
        s1 += p[(size_t)(r + 1) * (2 * D)];
        s2 += p[(size_t)(r + 2) * (2 * D)];
        s3 += p[(size_t)(r + 3) * (2 * D)];
    }
    ws_out[P2_OFF + (size_t)rg * (2 * D) + c] = (s0 + s1) + (s2 + s3);
}

// Stage B: NRG-deep sum over P2 + count reduce + output transform.
__global__ __launch_bounds__(BDIM_R)
void finalize_tree(const float* __restrict__ ws, float* __restrict__ out)
{
    const int i = blockIdx.x * BDIM_R + threadIdx.x;    // 0..1535
    // reduce the NBLK per-block mask counts (redundant per block, cheap)
    float c = 0.f;
    for (int r = threadIdx.x; r < NBLK; r += BDIM_R) c += ws[CNT_OFF + r];
#pragma unroll
    for (int m = 1; m < 64; m <<= 1) c += __shfl_xor(c, m);
    __shared__ float sc[BDIM_R / 64];
    if ((threadIdx.x & 63) == 0) sc[threadIdx.x >> 6] = c;
    __syncthreads();
    float csum = 0.f;
#pragma unroll
    for (int wv = 0; wv < BDIM_R / 64; ++wv) csum += sc[wv];
    const float cnt = fmaxf(csum, 1.f);

    if (i >= 2 * D) return;
    float s = 0.f;
#pragma unroll
    for (int g = 0; g < NRG; ++g) s += ws[P2_OFF + (size_t)g * (2 * D) + i];

    if (i < D) {
        float lu = s / cnt;
        // jnp.nan_to_num(nan=0, posinf=0.1, neginf=-0.1)
        if (isnan(lu)) lu = 0.f;
        else if (isinf(lu)) lu = (lu > 0.f) ? 0.1f : -0.1f;
        out[i] = 0.5f * lu;                      // WEIGHT_ROTE * loss_u
    } else {
        out[i] = 0.5f * (s * (1.f / 16384.f));   // WEIGHT_MSE * mse (loss_I == 0)
    }
}

// Atomic fallback finalize (tiny ws): ws[0..1535] sums, ws[1536] cnt.
__global__ __launch_bounds__(BDIM_R)
void finalize_atomic(const float* __restrict__ ws, float* __restrict__ out)
{
    const int i = blockIdx.x * BDIM_R + threadIdx.x;
    if (i >= 2 * D) return;
    const float cnt = fmaxf(ws[2 * D], 1.f);
    const float s = ws[i];
    if (i < D) {
        float lu = s / cnt;
        if (isnan(lu)) lu = 0.f;
        else if (isinf(lu)) lu = (lu > 0.f) ? 0.1f : -0.1f;
        out[i] = 0.5f * lu;
    } else {
        out[i] = 0.5f * (s * (1.f / 16384.f));
    }
}

extern "C" void kernel_launch(void* const* d_in, const int* in_sizes, int n_in,
                              void* d_out, int out_size, void* d_ws, size_t ws_size,
                              hipStream_t stream) {
    const float* init_img    = (const float*)d_in[0];
    const float* next_img    = (const float*)d_in[1];
    const float* init_unclip = (const float*)d_in[2];
    const float* pred_unclip = (const float*)d_in[3];
    float* ws  = (float*)d_ws;
    float* out = (float*)d_out;

    const size_t need = (P2_OFF + (size_t)NRG * 2 * D) * sizeof(float);
    if (ws_size >= need) {
        transform_loss_main<true><<<NBLK, BDIM, 0, stream>>>(
            init_img, next_img, init_unclip, pred_unclip, ws);
        reduce_partials<<<dim3((2 * D + BDIM_R - 1) / BDIM_R, NRG), BDIM_R, 0, stream>>>(ws, ws);
        finalize_tree<<<(2 * D + BDIM_R - 1) / BDIM_R, BDIM_R, 0, stream>>>(ws, out);
    } else {
        zero_ws_kernel<<<(2 * D + 1 + BDIM_R - 1) / BDIM_R, BDIM_R, 0, stream>>>(ws, 2 * D + 1);
        transform_loss_main<false><<<NBLK, BDIM, 0, stream>>>(
            init_img, next_img, init_unclip, pred_unclip, ws);
        finalize_atomic<<<(2 * D + BDIM_R - 1) / BDIM_R, BDIM_R, 0, stream>>>(ws, out);
    }
}

// Round 14
// 210.887 us; speedup vs baseline: 1.6629x; 1.0392x over previous
//
#include <hip/hip_runtime.h>
#include <math.h>

// TransformLoss on MI355X — round 13 kernel (resubmit; broker timeout in r13).
// Math (per row, d1 = init_img - next_img, d2 = init_unclip - pred_unclip):
//   A=sum d1^2, C=sum d2^2, AB=sum d1*d2, S1=sum d1, S2=sum d2
//   k=AB/A; W=C-AB*k; rA=1/sqrt(A); rW=1/sqrt(W); cos=clip(AB/(sqrt(A)sqrt(C)))
//   sin_a=sqrt(1-cos^2); cm1=cos-1; s1=S1*rA; s2=(S2-S1*k)*rW
//   p=cm1*s1-sin_a*s2; q=sin_a*s1+cm1*s2; c1=p*rA-q*k*rW; c2=q*rW
//   u[d]=c1*d1[d]+c2*d2[d]
//   loss_u[d]=0.5*nan_to_num(sum_masked u^2/cnt); mse[d]=0.5*mean((d1-d2)^2)
//
// r12 evidence: r1/r6/r7 all ~91-127us, 0.9-1.2 TB/s, latency-bound. Common
// cause: global loads issued from INSIDE the per-row reduction chain ->
// duty-cycle-weighted in-flight bytes < Little's-law requirement.
// r13 design:
//  - STAGE: 12 independent float4 loads/thread (192 B/lane in flight) for
//    tile t+1 issued BEFORE the barrier; diffs+LDS writes AFTER compute
//    (T14 issue-early/write-late). Double-buffered 4-row diff tiles (49 KB).
//  - COMPUTE: one wave per row from LDS (ds_read_b128 conflict-free,
//    12 cols/lane), single 30-swizzle butterfly, NO per-row barrier.
//    1 barrier per 4-row tile.
//  - Epilogue: LDS block-combine (reusing stage buffer) -> coalesced
//    per-block partial stores; r12's two-stage reduce tree unchanged.

constexpr int D      = 768;
constexpr int B_ROWS = 16384;
constexpr int BDIM   = 256;             // 4 waves
constexpr int WPB    = BDIM / 64;       // 4
constexpr int NBLK   = 1024;
constexpr int RPB    = B_ROWS / NBLK;   // 16 rows per block
constexpr int TR     = 4;               // tile rows (= waves)
constexpr int NT     = RPB / TR;        // 4 tiles
constexpr int CPL    = 3;               // float4 chunks per lane (12 cols)
constexpr int BDIM_R = 256;
constexpr int RG     = 64;
constexpr int NRG    = NBLK / RG;       // 16

// ws layout (floats):
//   [0 .. NBLK*1536)              P1: per-block partials (u^2[768] | mse[768])
//   [CNT_OFF .. CNT_OFF+NBLK)     per-block mask counts
//   [P2_OFF .. P2_OFF+NRG*1536)   P2: stage-A row-group partials
constexpr size_t CNT_OFF = (size_t)NBLK * 2 * D;
constexpr size_t P2_OFF  = CNT_OFF + NBLK;

__global__ void zero_ws_kernel(float* __restrict__ ws, int n) {
    int i = blockIdx.x * blockDim.x + threadIdx.x;
    if (i < n) ws[i] = 0.0f;
}

template <bool PARTIALS>
__global__ __launch_bounds__(BDIM, 3)   // cap regs ~170: room for 48 in-flight
void transform_loss_main(const float* __restrict__ gA,   // init_img
                         const float* __restrict__ gB,   // next_img
                         const float* __restrict__ gC,   // init_unclip
                         const float* __restrict__ gE,   // pred_unclip
                         float* __restrict__ ws)
{
    const int t    = threadIdx.x;
    const int lane = t & 63;
    const int wave = t >> 6;

    // double-buffered diff tiles: [buf][row][d1|d2][192 float4] = 49152 B
    __shared__ float4 lds4[2][TR][2][192];
    __shared__ float  cw[WPB];

    float acc_u[CPL][4], acc_m[CPL][4];
#pragma unroll
    for (int k = 0; k < CPL; ++k)
#pragma unroll
        for (int j = 0; j < 4; ++j) { acc_u[k][j] = 0.f; acc_m[k][j] = 0.f; }
    float lcnt = 0.f;

    const size_t row0 = (size_t)blockIdx.x * RPB;

    // stage slots: flat = s*256+t in [0,768): row = flat/192, colchunk = flat%192
    int srow[3], scc[3];
#pragma unroll
    for (int s = 0; s < 3; ++s) {
        const int flat = s * BDIM + t;
        srow[s] = flat / 192;
        scc[s]  = flat % 192;
    }

    float4 la[3], lb[3], lc[3], le[3];

    // prologue: load + stage tile 0 into buf 0
#pragma unroll
    for (int s = 0; s < 3; ++s) {
        const size_t g = (row0 + srow[s]) * D + (size_t)(scc[s] * 4);
        la[s] = *(const float4*)(gA + g);
        lb[s] = *(const float4*)(gB + g);
        lc[s] = *(const float4*)(gC + g);
        le[s] = *(const float4*)(gE + g);
    }
#pragma unroll
    for (int s = 0; s < 3; ++s) {
        float4 d1, d2;
        d1.x = la[s].x - lb[s].x; d1.y = la[s].y - lb[s].y;
        d1.z = la[s].z - lb[s].z; d1.w = la[s].w - lb[s].w;
        d2.x = lc[s].x - le[s].x; d2.y = lc[s].y - le[s].y;
        d2.z = lc[s].z - le[s].z; d2.w = lc[s].w - le[s].w;
        lds4[0][srow[s]][0][scc[s]] = d1;
        lds4[0][srow[s]][1][scc[s]] = d2;
    }

    int cur = 0;
    for (int tile = 0; tile < NT; ++tile) {
        // issue next tile's 12 loads EARLY (in flight through compute)
        if (tile + 1 < NT) {
#pragma unroll
            for (int s = 0; s < 3; ++s) {
                const size_t g = (row0 + (size_t)((tile + 1) * TR + srow[s])) * D
                               + (size_t)(scc[s] * 4);
                la[s] = *(const float4*)(gA + g);
                lb[s] = *(const float4*)(gB + g);
                lc[s] = *(const float4*)(gC + g);
                le[s] = *(const float4*)(gE + g);
            }
        }
        __syncthreads();   // buf[cur] fully staged (writes were before this)

        // ---- compute: wave handles row 'wave' of this tile, from LDS ----
        float4 v1[CPL], v2[CPL];
#pragma unroll
        for (int k = 0; k < CPL; ++k) {
            v1[k] = lds4[cur][wave][0][k * 64 + lane];
            v2[k] = lds4[cur][wave][1][k * 64 + lane];
        }
        float pA = 0.f, pC = 0.f, pAB = 0.f, pS1 = 0.f, pS2 = 0.f;
#pragma unroll
        for (int k = 0; k < CPL; ++k) {
            const float x4[4] = {v1[k].x, v1[k].y, v1[k].z, v1[k].w};
            const float y4[4] = {v2[k].x, v2[k].y, v2[k].z, v2[k].w};
#pragma unroll
            for (int j = 0; j < 4; ++j) {
                pA  = fmaf(x4[j], x4[j], pA);
                pC  = fmaf(y4[j], y4[j], pC);
                pAB = fmaf(x4[j], y4[j], pAB);
                pS1 += x4[j];
                pS2 += y4[j];
                const float md = x4[j] - y4[j];          // mse, unmasked
                acc_m[k][j] = fmaf(md, md, acc_m[k][j]);
            }
        }
        // single 64-lane butterfly per row (no cross-wave exchange needed)
#pragma unroll
        for (int m = 1; m < 64; m <<= 1) {
            pA  += __shfl_xor(pA,  m);
            pC  += __shfl_xor(pC,  m);
            pAB += __shfl_xor(pAB, m);
            pS1 += __shfl_xor(pS1, m);
            pS2 += __shfl_xor(pS2, m);
        }
        if (pA > 1e-16f) {   // ||d1|| > 1e-8 (wave-uniform)
            lcnt += 1.f;
            const float nA  = sqrtf(pA);
            const float rA  = 1.f / nA;
            const float nC  = sqrtf(pC);
            float cosang = pAB / (nA * nC);
            cosang = fminf(fmaxf(cosang, -1.f), 1.f);
            const float sin_a = sqrtf(fmaxf(1.f - cosang * cosang, 0.f));
            const float cm1 = cosang - 1.f;
            const float kk  = pAB / pA;
            const float W   = pC - pAB * kk;       // C - AB^2/A
            const float rW  = 1.f / sqrtf(W);
            const float s1  = pS1 * rA;
            const float s2  = (pS2 - pS1 * kk) * rW;
            const float p   = cm1 * s1 - sin_a * s2;
            const float q   = sin_a * s1 + cm1 * s2;
            const float c1  = p * rA - q * kk * rW;
            const float c2  = q * rW;
#pragma unroll
            for (int k = 0; k < CPL; ++k) {
                const float x4[4] = {v1[k].x, v1[k].y, v1[k].z, v1[k].w};
                const float y4[4] = {v2[k].x, v2[k].y, v2[k].z, v2[k].w};
#pragma unroll
                for (int j = 0; j < 4; ++j) {
                    const float u = fmaf(x4[j], c1, y4[j] * c2);
                    acc_u[k][j] = fmaf(u, u, acc_u[k][j]);
                }
            }
        }

        // ---- write-late: stage tile t+1 into the other buffer ----
        if (tile + 1 < NT) {
#pragma unroll
            for (int s = 0; s < 3; ++s) {
                float4 d1, d2;
                d1.x = la[s].x - lb[s].x; d1.y = la[s].y - lb[s].y;
                d1.z = la[s].z - lb[s].z; d1.w = la[s].w - lb[s].w;
                d2.x = lc[s].x - le[s].x; d2.y = lc[s].y - le[s].y;
                d2.z = lc[s].z - le[s].z; d2.w = lc[s].w - le[s].w;
                lds4[cur ^ 1][srow[s]][0][scc[s]] = d1;
                lds4[cur ^ 1][srow[s]][1][scc[s]] = d2;
            }
        }
        cur ^= 1;
    }

    // ---- epilogue: block-combine via reused stage LDS ----
    __syncthreads();                       // all compute reads done
    float4* f4 = (float4*)lds4;
    // u: f4[wave*192 + k*64 + lane]; m: f4[768 + wave*192 + k*64 + lane]
#pragma unroll
    for (int k = 0; k < CPL; ++k) {
        f4[wave * 192 + k * 64 + lane] =
            make_float4(acc_u[k][0], acc_u[k][1], acc_u[k][2], acc_u[k][3]);
        f4[768 + wave * 192 + k * 64 + lane] =
            make_float4(acc_m[k][0], acc_m[k][1], acc_m[k][2], acc_m[k][3]);
    }
    if (lane == 0) cw[wave] = lcnt;
    __syncthreads();

    const float* f = (const float*)f4;     // u: f[w*768+c]; m: f[3072+w*768+c]
    if (PARTIALS) {
        float* pb = ws + (size_t)blockIdx.x * (2 * D);
#pragma unroll
        for (int i = 0; i < 3; ++i) {
            const int c = t + i * 256;     // 0..767
            const float su = (f[c] + f[768 + c]) + (f[1536 + c] + f[2304 + c]);
            const float sm = (f[3072 + c] + f[3840 + c]) + (f[4608 + c] + f[5376 + c]);
            pb[c]     = su;
            pb[D + c] = sm;
        }
        if (t == 0) ws[CNT_OFF + blockIdx.x] = (cw[0] + cw[1]) + (cw[2] + cw[3]);
    } else {
#pragma unroll
        for (int i = 0; i < 3; ++i) {
            const int c = t + i * 256;
            const float su = (f[c] + f[768 + c]) + (f[1536 + c] + f[2304 + c]);
            const float sm = (f[3072 + c] + f[3840 + c]) + (f[4608 + c] + f[5376 + c]);
            atomicAdd(&ws[c], su);
            atomicAdd(&ws[D + c], sm);
        }
        if (t == 0) atomicAdd(&ws[2 * D], (cw[0] + cw[1]) + (cw[2] + cw[3]));
    }
}

// Stage A: grid (6, NRG); each thread sums RG=64 rows of one column.
__global__ __launch_bounds__(BDIM_R)
void reduce_partials(const float* __restrict__ ws_in, float* __restrict__ ws_out)
{
    const int c  = blockIdx.x * BDIM_R + threadIdx.x;   // 0..1535
    const int rg = blockIdx.y;                          // 0..NRG-1
    if (c >= 2 * D) return;
    const float* p = ws_in + (size_t)rg * RG * (2 * D) + c;
    float s0 = 0.f, s1 = 0.f, s2 = 0.f, s3 = 0.f;
#pragma unroll 4
    for (int r = 0; r < RG; r += 4) {
        s0 += p[(size_t)(r + 0) * (2 * D)];
        s1 += p[(size_t)(r + 1) * (2 * D)];
        s2 += p[(size_t)(r + 2) * (2 * D)];
        s3 += p[(size_t)(r + 3) * (2 * D)];
    }
    ws_out[P2_OFF + (size_t)rg * (2 * D) + c] = (s0 + s1) + (s2 + s3);
}

// Stage B: NRG-deep sum over P2 + count reduce + output transform.
__global__ __launch_bounds__(BDIM_R)
void finalize_tree(const float* __restrict__ ws, float* __restrict__ out)
{
    const int i = blockIdx.x * BDIM_R + threadIdx.x;    // 0..1535
    float c = 0.f;
    for (int r = threadIdx.x; r < NBLK; r += BDIM_R) c += ws[CNT_OFF + r];
#pragma unroll
    for (int m = 1; m < 64; m <<= 1) c += __shfl_xor(c, m);
    __shared__ float sc[BDIM_R / 64];
    if ((threadIdx.x & 63) == 0) sc[threadIdx.x >> 6] = c;
    __syncthreads();
    float csum = 0.f;
#pragma unroll
    for (int wv = 0; wv < BDIM_R / 64; ++wv) csum += sc[wv];
    const float cnt = fmaxf(csum, 1.f);

    if (i >= 2 * D) return;
    float s = 0.f;
#pragma unroll
    for (int g = 0; g < NRG; ++g) s += ws[P2_OFF + (size_t)g * (2 * D) + i];

    if (i < D) {
        float lu = s / cnt;
        if (isnan(lu)) lu = 0.f;
        else if (isinf(lu)) lu = (lu > 0.f) ? 0.1f : -0.1f;
        out[i] = 0.5f * lu;                      // WEIGHT_ROTE * loss_u
    } else {
        out[i] = 0.5f * (s * (1.f / 16384.f));   // WEIGHT_MSE * mse (loss_I == 0)
    }
}

// Atomic fallback finalize (tiny ws): ws[0..1535] sums, ws[1536] cnt.
__global__ __launch_bounds__(BDIM_R)
void finalize_atomic(const float* __restrict__ ws, float* __restrict__ out)
{
    const int i = blockIdx.x * BDIM_R + threadIdx.x;
    if (i >= 2 * D) return;
    const float cnt = fmaxf(ws[2 * D], 1.f);
    const float s = ws[i];
    if (i < D) {
        float lu = s / cnt;
        if (isnan(lu)) lu = 0.f;
        else if (isinf(lu)) lu = (lu > 0.f) ? 0.1f : -0.1f;
        out[i] = 0.5f * lu;
    } else {
        out[i] = 0.5f * (s * (1.f / 16384.f));
    }
}

extern "C" void kernel_launch(void* const* d_in, const int* in_sizes, int n_in,
                              void* d_out, int out_size, void* d_ws, size_t ws_size,
                              hipStream_t stream) {
    const float* init_img    = (const float*)d_in[0];
    const float* next_img    = (const float*)d_in[1];
    const float* init_unclip = (const float*)d_in[2];
    const float* pred_unclip = (const float*)d_in[3];
    float* ws  = (float*)d_ws;
    float* out = (float*)d_out;

    const size_t need = (P2_OFF + (size_t)NRG * 2 * D) * sizeof(float);
    if (ws_size >= need) {
        transform_loss_main<true><<<NBLK, BDIM, 0, stream>>>(
            init_img, next_img, init_unclip, pred_unclip, ws);
        reduce_partials<<<dim3((2 * D + BDIM_R - 1) / BDIM_R, NRG), BDIM_R, 0, stream>>>(ws, ws);
        finalize_tree<<<(2 * D + BDIM_R - 1) / BDIM_R, BDIM_R, 0, stream>>>(ws, out);
    } else {
        zero_ws_kernel<<<(2 * D + 1 + BDIM_R - 1) / BDIM_R, BDIM_R, 0, stream>>>(ws, 2 * D + 1);
        transform_loss_main<false><<<NBLK, BDIM, 0, stream>>>(
            init_img, next_img, init_unclip, pred_unclip, ws);
        finalize_atomic<<<(2 * D + BDIM_R - 1) / BDIM_R, BDIM_R, 0, stream>>>(ws, out);
    }
}